// Round 6
// baseline (155.980 us; speedup 1.0000x reference)
//
#include <hip/hip_runtime.h>
#include <math.h>

#define DIM 160
#define NB 2
#define CHUNK 5
#define NCHZ (DIM / CHUNK)   // 32
#define NTHREADS 256
#define EPS_F 1.1920928955078125e-07f

// ws layout (doubles):
// [0..1] sum_mask[n], [2..3] sum_norm_pred[n], [4..5] sum_norm_tgt[n],
// [6] sum inner^2, [8..9] c_pred[n], [10..11] c_tgt[n]

__device__ __forceinline__ float4 ldv(const float* __restrict__ p, bool ok) {
  float4 r = make_float4(0.f, 0.f, 0.f, 0.f);
  if (ok) r = *(const float4*)p;
  return r;
}

// Issue the 9 independent aligned float4 loads of one plane's 3 rows (L/M/R).
__device__ __forceinline__ void issue_plane(const float* __restrict__ img, int z, int y, int xb,
                                            bool ym, bool yp, bool xl, bool xr,
                                            float4 (&B)[9]) {
  const bool zok = ((unsigned)z < DIM);
  const int off0 = (z * DIM + y) * DIM + xb;
#pragma unroll
  for (int r = 0; r < 3; ++r) {
    const bool rv = zok && (r == 0 ? ym : (r == 2 ? yp : true));
    const int offr = off0 + (r - 1) * DIM;
    B[r * 3 + 0] = ldv(img + offr - 4, rv && xl);
    B[r * 3 + 1] = ldv(img + offr, rv);
    B[r * 3 + 2] = ldv(img + offr + 4, rv && xr);
  }
}

// P1 = diff_x*smooth_y, P2 = smooth_x*diff_y, P3 = smooth_x*smooth_y for 4 voxels.
__device__ __forceinline__ void compute_P(const float4 (&B)[9],
                                          float (&P1)[4], float (&P2)[4], float (&P3)[4]) {
#pragma unroll
  for (int r = 0; r < 3; ++r) {
    const float4 L = B[r * 3 + 0], M = B[r * 3 + 1], R = B[r * 3 + 2];
    const float fm1 = L.w, f0 = M.x, f1 = M.y, f2 = M.z, f3 = M.w, f4 = R.x;
    float S[4], D[4];
    S[0] = fm1 + 2.f * f0 + f1;  D[0] = f1 - fm1;
    S[1] = f0 + 2.f * f1 + f2;   D[1] = f2 - f0;
    S[2] = f1 + 2.f * f2 + f3;   D[2] = f3 - f1;
    S[3] = f2 + 2.f * f3 + f4;   D[3] = f4 - f2;
    if (r == 0) {
#pragma unroll
      for (int j = 0; j < 4; ++j) { P1[j] = D[j]; P2[j] = -S[j]; P3[j] = S[j]; }
    } else if (r == 1) {
#pragma unroll
      for (int j = 0; j < 4; ++j) { P1[j] += 2.f * D[j]; P3[j] += 2.f * S[j]; }
    } else {
#pragma unroll
      for (int j = 0; j < 4; ++j) { P1[j] += D[j]; P2[j] += S[j]; P3[j] += S[j]; }
    }
  }
}

// One pipelined step of pass1. I is a literal; CUR/NXT are the ping-pong plane
// buffers; MC/MN the ping-pong mask prefetch registers.
#define P1STEP(I, CUR, NXT, MC, MN)                                              \
  {                                                                              \
    const int z = zs - 1 + (I);                                                  \
    if ((I) <= CHUNK) issue_plane(img, z + 1, y, xb, ym, yp, xl, xr, NXT);       \
    if (im == 0 && (I) >= 1 && (I) <= CHUNK)                                     \
      MN = *(const float4*)(mb + (z * DIM + y) * DIM + xb);                      \
    float P1[4], P2[4], P3[4];                                                   \
    compute_P(CUR, P1, P2, P3);                                                  \
    const int sA = (I) & 1, sB = sA ^ 1;                                         \
    if ((I) >= 2) {                                                              \
      if (im == 0) {                                                             \
        const float m4[4] = {MC.x, MC.y, MC.z, MC.w};                            \
        _Pragma("unroll")                                                        \
        for (int j = 0; j < 4; ++j) {                                            \
          float gx = OUT[sA][0][j] + P1[j];                                      \
          float gy = OUT[sA][1][j] + P2[j];                                      \
          float gz = OUT[sA][2][j] + P3[j];                                      \
          am += m4[j];                                                           \
          an += sqrtf(gx * gx + gy * gy + gz * gz + EPS_F) * m4[j];              \
        }                                                                        \
      } else {                                                                   \
        _Pragma("unroll")                                                        \
        for (int j = 0; j < 4; ++j) {                                            \
          float gx = OUT[sA][0][j] + P1[j];                                      \
          float gy = OUT[sA][1][j] + P2[j];                                      \
          float gz = OUT[sA][2][j] + P3[j];                                      \
          an += sqrtf(gx * gx + gy * gy + gz * gz + EPS_F);                      \
        }                                                                        \
      }                                                                          \
    }                                                                            \
    _Pragma("unroll")                                                            \
    for (int j = 0; j < 4; ++j) {                                                \
      OUT[sA][0][j] = P1[j];                                                     \
      OUT[sA][1][j] = P2[j];                                                     \
      OUT[sA][2][j] = -P3[j];                                                    \
      OUT[sB][0][j] += 2.f * P1[j];                                              \
      OUT[sB][1][j] += 2.f * P2[j];                                              \
    }                                                                            \
  }

__global__ __launch_bounds__(NTHREADS)
void pass1_kernel(const float* __restrict__ pred, const float* __restrict__ tgt,
                  const float* __restrict__ mask, double* __restrict__ ws) {
  __shared__ float red[2][4];
  const int tid = threadIdx.x;
  const int tx = tid & 7, ty = tid >> 3;
  int bz = blockIdx.z;
  const int im = bz & 1; bz >>= 1;
  const int n = bz / NCHZ;
  const int zs = (bz % NCHZ) * CHUNK;
  const int xb = blockIdx.x * 32 + tx * 4;
  const int y = blockIdx.y * 32 + ty;
  const size_t base = (size_t)n * DIM * DIM * DIM;
  const float* img = (im == 0 ? pred : tgt) + base;
  const float* mb = mask + base;

  const bool xl = (xb >= 4), xr = (xb + 4 < DIM);
  const bool ym = (y >= 1), yp = (y <= DIM - 2);

  float OUT[2][3][4];
#pragma unroll
  for (int s = 0; s < 2; ++s)
#pragma unroll
    for (int f = 0; f < 3; ++f)
#pragma unroll
      for (int j = 0; j < 4; ++j) OUT[s][f][j] = 0.f;

  float am = 0.f, an = 0.f;
  float4 BUF0[9], BUF1[9];
  float4 MA = make_float4(0.f, 0.f, 0.f, 0.f), MB = MA;

  issue_plane(img, zs - 1, y, xb, ym, yp, xl, xr, BUF0);

  P1STEP(0, BUF0, BUF1, MA, MA)
  P1STEP(1, BUF1, BUF0, MA, MA)
  P1STEP(2, BUF0, BUF1, MA, MB)
  P1STEP(3, BUF1, BUF0, MB, MA)
  P1STEP(4, BUF0, BUF1, MA, MB)
  P1STEP(5, BUF1, BUF0, MB, MA)
  P1STEP(6, BUF0, BUF1, MA, MB)

  float v0 = am, v1 = an;
#pragma unroll
  for (int off = 32; off > 0; off >>= 1) {
    v0 += __shfl_down(v0, off, 64);
    v1 += __shfl_down(v1, off, 64);
  }
  const int lane = tid & 63, wave = tid >> 6;
  if (lane == 0) { red[0][wave] = v0; red[1][wave] = v1; }
  __syncthreads();
  if (tid == 0) {
    if (im == 0) atomicAdd(&ws[0 + n], (double)(red[0][0] + red[0][1] + red[0][2] + red[0][3]));
    atomicAdd(&ws[2 + 2 * im + n], (double)(red[1][0] + red[1][1] + red[1][2] + red[1][3]));
  }
}

__global__ void compute_c_kernel(double* __restrict__ ws) {
  if (threadIdx.x == 0 && blockIdx.x == 0) {
    for (int n = 0; n < NB; ++n) {
      double inv_m = 1.0 / ws[0 + n];
      double ae_p = ws[2 + n] * inv_m;  // eta = 1.0
      double ae_t = ws[4 + n] * inv_m;
      ws[8 + n] = ae_p * ae_p + (double)EPS_F;
      ws[10 + n] = ae_t * ae_t + (double)EPS_F;
    }
  }
}

__global__ __launch_bounds__(NTHREADS)
void pass2_kernel(const float* __restrict__ pred, const float* __restrict__ tgt,
                  double* __restrict__ ws) {
  __shared__ float red[4];
  const int tid = threadIdx.x;
  const int tx = tid & 7, ty = tid >> 3;
  const int bz = blockIdx.z;
  const int n = bz / NCHZ;
  const int zs = (bz % NCHZ) * CHUNK;
  const int xb = blockIdx.x * 32 + tx * 4;
  const int y = blockIdx.y * 32 + ty;
  const size_t base = (size_t)n * DIM * DIM * DIM;
  const float* pb = pred + base;
  const float* tb = tgt + base;

  const float cp = (float)ws[8 + n];
  const float ct = (float)ws[10 + n];

  const bool xl = (xb >= 4), xr = (xb + 4 < DIM);
  const bool ym = (y >= 1), yp = (y <= DIM - 2);

  float OUT[2][2][3][4];  // [slot][img][field][j]
#pragma unroll
  for (int s = 0; s < 2; ++s)
#pragma unroll
    for (int g = 0; g < 2; ++g)
#pragma unroll
      for (int f = 0; f < 3; ++f)
#pragma unroll
        for (int j = 0; j < 4; ++j) OUT[s][g][f][j] = 0.f;

  float acc = 0.f;
  float4 PB[9], TB[9];

  issue_plane(pb, zs - 1, y, xb, ym, yp, xl, xr, PB);
  issue_plane(tb, zs - 1, y, xb, ym, yp, xl, xr, TB);

#pragma unroll
  for (int i = 0; i <= CHUNK + 1; ++i) {
    const int z = zs - 1 + i;
    float Pp1[4], Pp2[4], Pp3[4], Pt1[4], Pt2[4], Pt3[4];
    // compute pred's plane while tgt's loads are in flight, and vice versa
    compute_P(PB, Pp1, Pp2, Pp3);
    if (i <= CHUNK) issue_plane(pb, z + 1, y, xb, ym, yp, xl, xr, PB);
    compute_P(TB, Pt1, Pt2, Pt3);
    if (i <= CHUNK) issue_plane(tb, z + 1, y, xb, ym, yp, xl, xr, TB);

    const int sA = i & 1, sB = sA ^ 1;
    if (i >= 2) {
#pragma unroll
      for (int j = 0; j < 4; ++j) {
        float gpx = OUT[sA][0][0][j] + Pp1[j];
        float gpy = OUT[sA][0][1][j] + Pp2[j];
        float gpz = OUT[sA][0][2][j] + Pp3[j];
        float gtx = OUT[sA][1][0][j] + Pt1[j];
        float gty = OUT[sA][1][1][j] + Pt2[j];
        float gtz = OUT[sA][1][2][j] + Pt3[j];
        float sqp = gpx * gpx + gpy * gpy + gpz * gpz;
        float sqt = gtx * gtx + gty * gty + gtz * gtz;
        float dot = gpx * gtx + gpy * gty + gpz * gtz;
        float inner = dot * rsqrtf((sqp + cp) * (sqt + ct));
        acc += inner * inner;
      }
    }
#pragma unroll
    for (int j = 0; j < 4; ++j) {
      OUT[sA][0][0][j] = Pp1[j];
      OUT[sA][0][1][j] = Pp2[j];
      OUT[sA][0][2][j] = -Pp3[j];
      OUT[sB][0][0][j] += 2.f * Pp1[j];
      OUT[sB][0][1][j] += 2.f * Pp2[j];
      OUT[sA][1][0][j] = Pt1[j];
      OUT[sA][1][1][j] = Pt2[j];
      OUT[sA][1][2][j] = -Pt3[j];
      OUT[sB][1][0][j] += 2.f * Pt1[j];
      OUT[sB][1][1][j] += 2.f * Pt2[j];
    }
  }

#pragma unroll
  for (int off = 32; off > 0; off >>= 1) acc += __shfl_down(acc, off, 64);
  const int lane = tid & 63, wave = tid >> 6;
  if (lane == 0) red[wave] = acc;
  __syncthreads();
  if (tid == 0) atomicAdd(&ws[6], (double)(red[0] + red[1] + red[2] + red[3]));
}

__global__ void finalize_kernel(const double* __restrict__ ws, float* __restrict__ out) {
  if (threadIdx.x == 0 && blockIdx.x == 0) {
    double mean = ws[6] / ((double)NB * DIM * DIM * DIM);
    out[0] = (float)(1.0 - mean);
  }
}

extern "C" void kernel_launch(void* const* d_in, const int* in_sizes, int n_in,
                              void* d_out, int out_size, void* d_ws, size_t ws_size,
                              hipStream_t stream) {
  const float* pred = (const float*)d_in[0];
  const float* tgt = (const float*)d_in[1];
  const float* mask = (const float*)d_in[2];
  float* out = (float*)d_out;
  double* ws = (double*)d_ws;

  hipMemsetAsync(d_ws, 0, 16 * sizeof(double), stream);

  dim3 grid1(DIM / 32, DIM / 32, NCHZ * NB * 2);  // 3200 blocks
  pass1_kernel<<<grid1, NTHREADS, 0, stream>>>(pred, tgt, mask, ws);
  compute_c_kernel<<<1, 64, 0, stream>>>(ws);
  dim3 grid2(DIM / 32, DIM / 32, NCHZ * NB);      // 1600 blocks
  pass2_kernel<<<grid2, NTHREADS, 0, stream>>>(pred, tgt, ws);
  finalize_kernel<<<1, 64, 0, stream>>>(ws, out);
}